// Round 1
// baseline (65961.938 us; speedup 1.0000x reference)
//
#include <hip/hip_runtime.h>
#include <hip/hip_bf16.h>

#define BSZ 32
#define TT 50
#define NN 192
#define HH 32
#define NSTEP (TT - 1)

__device__ __forceinline__ float fast_rcp(float x) { return __builtin_amdgcn_rcpf(x); }

__device__ __forceinline__ float fast_tanh(float x) {
    // tanh(x) = 1 - 2/(exp(2x)+1); robust at +-inf (exp->inf => 1, exp->0 => -1)
    float e = __expf(2.0f * x);
    return 1.0f - 2.0f * fast_rcp(e + 1.0f);
}

__device__ __forceinline__ float fast_sigmoid(float x) {
    return fast_rcp(1.0f + __expf(-x));
}

__device__ __forceinline__ float relu(float x) { return x > 0.0f ? x : 0.0f; }

// 32-dim dot of register vector x with an LDS row (wave-uniform broadcast reads)
__device__ __forceinline__ float mv32(const float* x, const float* sw_row) {
    float y = 0.0f;
#pragma unroll
    for (int k4 = 0; k4 < 8; ++k4) {
        float4 w = ((const float4*)sw_row)[k4];
        y += x[4 * k4 + 0] * w.x + x[4 * k4 + 1] * w.y +
             x[4 * k4 + 2] * w.z + x[4 * k4 + 3] * w.w;
    }
    return y;
}

// ---------------- K1: message aggregation ----------------
// grid = BSZ*NN blocks (one per (b,r)), 64 threads. Lane owns s (3 iterations).
__global__ __launch_bounds__(64) void k_agg(
    const float* __restrict__ send_p,  // [BSZ][NN][HH]
    const float* __restrict__ recv_p,  // [BSZ][NN][HH]
    const float* __restrict__ adj,     // [BSZ][NN][NN]
    const float* __restrict__ W2,      // [HH][HH]
    const float* __restrict__ b1,      // [HH]
    const float* __restrict__ b2,      // [HH]
    float* __restrict__ agg)           // [BSZ][NN][HH]
{
    __shared__ float sW2[HH * HH];
    __shared__ float sb1[HH];
    __shared__ float sb2[HH];

    const int tid = threadIdx.x;
    const int blk = blockIdx.x;         // b*NN + r
    const int b = blk / NN;

    for (int i = tid; i < HH * HH; i += 64) sW2[i] = W2[i];
    if (tid < HH) { sb1[tid] = b1[tid]; sb2[tid] = b2[tid]; }

    // recv vector for this (b,r): uniform across lanes, keep in registers
    float rv[HH];
    const float* rp = recv_p + (size_t)blk * HH;
#pragma unroll
    for (int k4 = 0; k4 < 8; ++k4) {
        float4 v = ((const float4*)rp)[k4];
        rv[4 * k4 + 0] = v.x; rv[4 * k4 + 1] = v.y;
        rv[4 * k4 + 2] = v.z; rv[4 * k4 + 3] = v.w;
    }
    __syncthreads();

    float acc[HH];
#pragma unroll
    for (int k = 0; k < HH; ++k) acc[k] = 0.0f;

    const float* adj_row = adj + (size_t)blk * NN;

    for (int s0 = 0; s0 < NN; s0 += 64) {
        const int s = s0 + tid;
        const float* sp = send_p + ((size_t)b * NN + s) * HH;

        float m1[HH];
#pragma unroll
        for (int k4 = 0; k4 < 8; ++k4) {
            float4 v = ((const float4*)sp)[k4];
            m1[4 * k4 + 0] = fast_tanh(rv[4 * k4 + 0] + v.x + sb1[4 * k4 + 0]);
            m1[4 * k4 + 1] = fast_tanh(rv[4 * k4 + 1] + v.y + sb1[4 * k4 + 1]);
            m1[4 * k4 + 2] = fast_tanh(rv[4 * k4 + 2] + v.z + sb1[4 * k4 + 2]);
            m1[4 * k4 + 3] = fast_tanh(rv[4 * k4 + 3] + v.w + sb1[4 * k4 + 3]);
        }

        const float adjv = adj_row[s];
#pragma unroll
        for (int ho = 0; ho < HH; ++ho) {
            float y = sb2[ho] + mv32(m1, sW2 + ho * HH);
            acc[ho] += adjv * fast_tanh(y);
        }
    }

    // butterfly reduce over the 64 lanes (every lane ends with the total)
#pragma unroll
    for (int m = 1; m < 64; m <<= 1) {
#pragma unroll
        for (int k = 0; k < HH; ++k) acc[k] += __shfl_xor(acc[k], m, 64);
    }

    if (tid == 0) {
        float* o = agg + (size_t)blk * HH;
#pragma unroll
        for (int k4 = 0; k4 < 8; ++k4) {
            float4 v;
            v.x = acc[4 * k4 + 0] * (1.0f / (float)NN);
            v.y = acc[4 * k4 + 1] * (1.0f / (float)NN);
            v.z = acc[4 * k4 + 2] * (1.0f / (float)NN);
            v.w = acc[4 * k4 + 3] * (1.0f / (float)NN);
            ((float4*)o)[k4] = v;
        }
    }
}

// ---------------- K2: GRU update + send/recv proj + prediction head ----------------
// LDS weight layout offsets (floats)
#define WIR   (0 * HH * HH)
#define WII   (1 * HH * HH)
#define WIN_  (2 * HH * HH)
#define WHR   (3 * HH * HH)
#define WHI   (4 * HH * HH)
#define WHH   (5 * HH * HH)
#define WO1   (6 * HH * HH)
#define WO2   (7 * HH * HH)
#define WO3   (8 * HH * HH)
#define WSEND (9 * HH * HH)
#define WRECV (10 * HH * HH)
#define BIR   (11 * HH * HH + 0 * HH)
#define BII   (11 * HH * HH + 1 * HH)
#define BIN   (11 * HH * HH + 2 * HH)
#define BO1   (11 * HH * HH + 3 * HH)
#define BO2   (11 * HH * HH + 4 * HH)
#define BO3   (11 * HH * HH + 5 * HH)
#define SWTOT (11 * HH * HH + 6 * HH)

__global__ __launch_bounds__(256) void k_update(
    const int* __restrict__ skill,     // [BSZ][TT]
    const float* __restrict__ emb,     // [NN][HH]
    const float* __restrict__ agg,     // [BSZ][NN][HH]
    float* __restrict__ hidden,        // [BSZ][NN][HH]
    float* __restrict__ send_p,        // [BSZ][NN][HH]
    float* __restrict__ recv_p,        // [BSZ][NN][HH]
    const float* __restrict__ Wmsg1,   // [HH][2*HH]
    const float* __restrict__ W_hr, const float* __restrict__ W_hi,
    const float* __restrict__ W_hh,
    const float* __restrict__ W_ir, const float* __restrict__ b_ir,
    const float* __restrict__ W_ii, const float* __restrict__ b_ii,
    const float* __restrict__ W_in, const float* __restrict__ b_in,
    const float* __restrict__ W_o1, const float* __restrict__ b_o1,
    const float* __restrict__ W_o2, const float* __restrict__ b_o2,
    const float* __restrict__ W_o3, const float* __restrict__ b_o3,
    float* __restrict__ out,           // [BSZ][NSTEP][NN][HH]
    int t)
{
    __shared__ float sw[SWTOT];
    const int tid = threadIdx.x;

    // stage weights
    for (int i = tid; i < HH * HH; i += 256) {
        sw[WIR + i]  = W_ir[i];
        sw[WII + i]  = W_ii[i];
        sw[WIN_ + i] = W_in[i];
        sw[WHR + i]  = W_hr[i];
        sw[WHI + i]  = W_hi[i];
        sw[WHH + i]  = W_hh[i];
        sw[WO1 + i]  = W_o1[i];
        sw[WO2 + i]  = W_o2[i];
        sw[WO3 + i]  = W_o3[i];
        const int row = i >> 5, col = i & 31;
        sw[WSEND + i] = Wmsg1[row * 64 + col];
        sw[WRECV + i] = Wmsg1[row * 64 + 32 + col];
    }
    if (tid < HH) {
        sw[BIR + tid] = b_ir[tid];
        sw[BII + tid] = b_ii[tid];
        sw[BIN + tid] = b_in[tid];
        sw[BO1 + tid] = b_o1[tid];
        sw[BO2 + tid] = b_o2[tid];
        sw[BO3 + tid] = b_o3[tid];
    }
    __syncthreads();

    const int node = blockIdx.x * 256 + tid;   // < BSZ*NN
    const int b = node / NN;
    const int r = node - b * NN;

    float inp[HH], a[HH], hid[HH];
    const float* erow = emb + (size_t)skill[b * TT + t] * HH;
    const float* arow = agg + (size_t)node * HH;
    float* hrow = hidden + (size_t)node * HH;
#pragma unroll
    for (int k4 = 0; k4 < 8; ++k4) {
        float4 v = ((const float4*)erow)[k4];
        inp[4 * k4 + 0] = v.x; inp[4 * k4 + 1] = v.y;
        inp[4 * k4 + 2] = v.z; inp[4 * k4 + 3] = v.w;
        float4 av = ((const float4*)arow)[k4];
        a[4 * k4 + 0] = av.x; a[4 * k4 + 1] = av.y;
        a[4 * k4 + 2] = av.z; a[4 * k4 + 3] = av.w;
        float4 hv = ((const float4*)hrow)[k4];
        hid[4 * k4 + 0] = hv.x; hid[4 * k4 + 1] = hv.y;
        hid[4 * k4 + 2] = hv.z; hid[4 * k4 + 3] = hv.w;
    }

    float rg[HH], ig[HH], hn[HH];
#pragma unroll
    for (int ho = 0; ho < HH; ++ho)
        rg[ho] = fast_sigmoid(sw[BIR + ho] + mv32(inp, sw + WIR + ho * HH) +
                              mv32(a, sw + WHR + ho * HH));
#pragma unroll
    for (int ho = 0; ho < HH; ++ho)
        ig[ho] = fast_sigmoid(sw[BII + ho] + mv32(inp, sw + WII + ho * HH) +
                              mv32(a, sw + WHI + ho * HH));
#pragma unroll
    for (int ho = 0; ho < HH; ++ho) {
        float nst = fast_tanh(sw[BIN + ho] + mv32(inp, sw + WIN_ + ho * HH) +
                              rg[ho] * mv32(a, sw + WHH + ho * HH));
        hn[ho] = (1.0f - ig[ho]) * nst + ig[ho] * hid[ho];
    }

    // store new hidden
#pragma unroll
    for (int k4 = 0; k4 < 8; ++k4) {
        float4 v;
        v.x = hn[4 * k4 + 0]; v.y = hn[4 * k4 + 1];
        v.z = hn[4 * k4 + 2]; v.w = hn[4 * k4 + 3];
        ((float4*)hrow)[k4] = v;
    }

    // send/recv projections for the NEXT step
    float* srow = send_p + (size_t)node * HH;
    float* rrow = recv_p + (size_t)node * HH;
#pragma unroll
    for (int ho = 0; ho < HH; ++ho) {
        srow[ho] = mv32(hn, sw + WSEND + ho * HH);
        rrow[ho] = mv32(hn, sw + WRECV + ho * HH);
    }

    // prediction head
    float p1[HH], p2[HH];
#pragma unroll
    for (int ho = 0; ho < HH; ++ho)
        p1[ho] = relu(sw[BO1 + ho] + mv32(hn, sw + WO1 + ho * HH));
#pragma unroll
    for (int ho = 0; ho < HH; ++ho)
        p2[ho] = relu(sw[BO2 + ho] + mv32(p1, sw + WO2 + ho * HH));

    float* orow = out + (((size_t)b * NSTEP + t) * NN + r) * HH;
#pragma unroll
    for (int ho = 0; ho < HH; ++ho)
        orow[ho] = sw[BO3 + ho] + mv32(p2, sw + WO3 + ho * HH);
}

extern "C" void kernel_launch(void* const* d_in, const int* in_sizes, int n_in,
                              void* d_out, int out_size, void* d_ws, size_t ws_size,
                              hipStream_t stream) {
    const int*   skill = (const int*)d_in[0];
    const float* adj   = (const float*)d_in[1];
    const float* emb   = (const float*)d_in[2];
    const float* Wmsg1 = (const float*)d_in[3];
    const float* bmsg1 = (const float*)d_in[4];
    const float* Wmsg2 = (const float*)d_in[5];
    const float* bmsg2 = (const float*)d_in[6];
    const float* W_hr  = (const float*)d_in[7];
    const float* W_hi  = (const float*)d_in[8];
    const float* W_hh  = (const float*)d_in[9];
    const float* W_ir  = (const float*)d_in[10];
    const float* b_ir  = (const float*)d_in[11];
    const float* W_ii  = (const float*)d_in[12];
    const float* b_ii  = (const float*)d_in[13];
    const float* W_in  = (const float*)d_in[14];
    const float* b_in  = (const float*)d_in[15];
    const float* W_o1  = (const float*)d_in[16];
    const float* b_o1  = (const float*)d_in[17];
    const float* W_o2  = (const float*)d_in[18];
    const float* b_o2  = (const float*)d_in[19];
    const float* W_o3  = (const float*)d_in[20];
    const float* b_o3  = (const float*)d_in[21];
    float* out = (float*)d_out;

    const size_t NH = (size_t)BSZ * NN * HH;   // 196608
    float* hidden = (float*)d_ws;
    float* sendp  = hidden + NH;
    float* recvp  = sendp + NH;
    float* aggb   = recvp + NH;

    // hidden = send_p = recv_p = 0 at t=0 (contiguous)
    hipMemsetAsync(hidden, 0, 3 * NH * sizeof(float), stream);

    for (int t = 0; t < NSTEP; ++t) {
        k_agg<<<BSZ * NN, 64, 0, stream>>>(sendp, recvp, adj, Wmsg2, bmsg1, bmsg2, aggb);
        k_update<<<(BSZ * NN) / 256, 256, 0, stream>>>(
            skill, emb, aggb, hidden, sendp, recvp, Wmsg1,
            W_hr, W_hi, W_hh, W_ir, b_ir, W_ii, b_ii, W_in, b_in,
            W_o1, b_o1, W_o2, b_o2, W_o3, b_o3, out, t);
    }
}

// Round 2
// 2009.406 us; speedup vs baseline: 32.8266x; 32.8266x over previous
//
#include <hip/hip_runtime.h>
#include <hip/hip_bf16.h>

#define BSZ 32
#define TT 50
#define NN 192
#define HH 32
#define NSTEP (TT - 1)

typedef __attribute__((ext_vector_type(8))) short bf16x8;
typedef __attribute__((ext_vector_type(4))) float f32x4;

__device__ __forceinline__ float fast_rcp(float x) { return __builtin_amdgcn_rcpf(x); }

__device__ __forceinline__ float fast_tanh(float x) {
    // tanh(x) = 1 - 2/(exp(2x)+1); robust at +-inf
    float e = __expf(2.0f * x);
    return 1.0f - 2.0f * fast_rcp(e + 1.0f);
}

__device__ __forceinline__ float fast_sigmoid(float x) {
    return fast_rcp(1.0f + __expf(-x));
}

__device__ __forceinline__ float relu(float x) { return x > 0.0f ? x : 0.0f; }

// float -> bf16 (RNE)
__device__ __forceinline__ short f2bf(float x) {
    union { float f; unsigned u; } v; v.f = x;
    unsigned r = (v.u + 0x7FFFu + ((v.u >> 16) & 1u)) >> 16;
    return (short)r;
}

// ---------------- K1: message aggregation via MFMA ----------------
// One wave per (b,r). s tiled by 16 (12 tiles). A = m1 rows (s), B = W2^T, D[s,h].
// A-frag: lane holds A[lane&15][8*(lane>>4)+j]; B-frag: B[8*(lane>>4)+j][lane&15];
// C/D:    col = lane&15, row = 4*(lane>>4)+j   (m89-verified layout)
__global__ __launch_bounds__(256) void k_agg(
    const float* __restrict__ send_p,  // [BSZ][NN][HH]
    const float* __restrict__ recv_p,  // [BSZ][NN][HH]
    const float* __restrict__ adj,     // [BSZ][NN][NN]
    const float* __restrict__ W2,      // [HH][HH]
    const float* __restrict__ b1,      // [HH]
    const float* __restrict__ b2,      // [HH]
    float* __restrict__ agg)           // [BSZ][NN][HH]
{
    const int wid  = threadIdx.x >> 6;
    const int lane = threadIdx.x & 63;
    const int blk  = blockIdx.x * 4 + wid;   // b*NN + r
    const int b    = blk / NN;

    const int n16 = lane & 15;   // A-row within s-tile / B,D column (h within h-tile)
    const int kg  = lane >> 4;   // 0..3
    const int k8  = kg * 8;      // per-lane K-slice base

    // per-lane K-slice of recv-projection and b1 (uniform over s)
    float rv8[8], bb1[8];
    {
        const float4* rp4 = (const float4*)(recv_p + (size_t)blk * HH + k8);
        float4 r0 = rp4[0], r1 = rp4[1];
        rv8[0]=r0.x; rv8[1]=r0.y; rv8[2]=r0.z; rv8[3]=r0.w;
        rv8[4]=r1.x; rv8[5]=r1.y; rv8[6]=r1.z; rv8[7]=r1.w;
        const float4* bp4 = (const float4*)(b1 + k8);
        float4 c0 = bp4[0], c1 = bp4[1];
        bb1[0]=c0.x; bb1[1]=c0.y; bb1[2]=c0.z; bb1[3]=c0.w;
        bb1[4]=c1.x; bb1[5]=c1.y; bb1[6]=c1.z; bb1[7]=c1.w;
    }

    // B fragments (register-resident, wave-uniform over s-tiles):
    // B[k][n] = W2T[k][n] = W2[t*16+n16][k], lane covers k = k8..k8+7
    bf16x8 Bfrag0, Bfrag1;
    {
        const float4* w0 = (const float4*)(W2 + (size_t)(n16) * HH + k8);
        const float4* w1 = (const float4*)(W2 + (size_t)(16 + n16) * HH + k8);
        float4 a0 = w0[0], a1 = w0[1], d0 = w1[0], d1 = w1[1];
        Bfrag0[0]=f2bf(a0.x); Bfrag0[1]=f2bf(a0.y); Bfrag0[2]=f2bf(a0.z); Bfrag0[3]=f2bf(a0.w);
        Bfrag0[4]=f2bf(a1.x); Bfrag0[5]=f2bf(a1.y); Bfrag0[6]=f2bf(a1.z); Bfrag0[7]=f2bf(a1.w);
        Bfrag1[0]=f2bf(d0.x); Bfrag1[1]=f2bf(d0.y); Bfrag1[2]=f2bf(d0.z); Bfrag1[3]=f2bf(d0.w);
        Bfrag1[4]=f2bf(d1.x); Bfrag1[5]=f2bf(d1.y); Bfrag1[6]=f2bf(d1.z); Bfrag1[7]=f2bf(d1.w);
    }
    const float bb2_0 = b2[n16];
    const float bb2_1 = b2[16 + n16];

    const float* adj_row = adj + (size_t)blk * NN;
    const float* sbase   = send_p + (size_t)b * NN * HH;

    float acc0 = 0.0f, acc1 = 0.0f;

    for (int s0 = 0; s0 < NN; s0 += 16) {
        // A-frag: m1[s0+n16][k8+j] = tanh(rv + send + b1)
        const float4* sp4 = (const float4*)(sbase + (size_t)(s0 + n16) * HH + k8);
        float4 v0 = sp4[0], v1 = sp4[1];
        bf16x8 Afrag;
        Afrag[0] = f2bf(fast_tanh(rv8[0] + v0.x + bb1[0]));
        Afrag[1] = f2bf(fast_tanh(rv8[1] + v0.y + bb1[1]));
        Afrag[2] = f2bf(fast_tanh(rv8[2] + v0.z + bb1[2]));
        Afrag[3] = f2bf(fast_tanh(rv8[3] + v0.w + bb1[3]));
        Afrag[4] = f2bf(fast_tanh(rv8[4] + v1.x + bb1[4]));
        Afrag[5] = f2bf(fast_tanh(rv8[5] + v1.y + bb1[5]));
        Afrag[6] = f2bf(fast_tanh(rv8[6] + v1.z + bb1[6]));
        Afrag[7] = f2bf(fast_tanh(rv8[7] + v1.w + bb1[7]));

        f32x4 c0 = __builtin_amdgcn_mfma_f32_16x16x32_bf16(Afrag, Bfrag0, (f32x4){0.f,0.f,0.f,0.f}, 0, 0, 0);
        f32x4 c1 = __builtin_amdgcn_mfma_f32_16x16x32_bf16(Afrag, Bfrag1, (f32x4){0.f,0.f,0.f,0.f}, 0, 0, 0);

#pragma unroll
        for (int j = 0; j < 4; ++j) {
            const float adjv = adj_row[s0 + kg * 4 + j];
            acc0 += adjv * fast_tanh(c0[j] + bb2_0);
            acc1 += adjv * fast_tanh(c1[j] + bb2_1);
        }
    }

    // reduce across the 4 row-groups (lanes l, l+16, l+32, l+48)
    acc0 += __shfl_xor(acc0, 16, 64); acc0 += __shfl_xor(acc0, 32, 64);
    acc1 += __shfl_xor(acc1, 16, 64); acc1 += __shfl_xor(acc1, 32, 64);

    if (lane < 16) {
        float* o = agg + (size_t)blk * HH;
        o[lane]      = acc0 * (1.0f / (float)NN);
        o[16 + lane] = acc1 * (1.0f / (float)NN);
    }
}

// ---------------- K2: GRU update + send/recv proj + head ----------------
// 32 lanes per node, lane h owns element h. Weights in LDS padded to stride 33
// (bank = (h+k)%32, conflict-free). Matvec via __shfl broadcast within 32-lane group.
#define LROW 33
#define LMAT (HH * LROW)   // 1056 floats per matrix
#define M_IR 0
#define M_II 1
#define M_IN 2
#define M_HR 3
#define M_HI 4
#define M_HH 5
#define M_O1 6
#define M_O2 7
#define M_O3 8
#define M_SE 9
#define M_RE 10

__global__ __launch_bounds__(256) void k_update(
    const int* __restrict__ skill,     // [BSZ][TT]
    const float* __restrict__ emb,     // [NN][HH]
    const float* __restrict__ agg,     // [BSZ][NN][HH]
    float* __restrict__ hidden,        // [BSZ][NN][HH]
    float* __restrict__ send_p,        // [BSZ][NN][HH]
    float* __restrict__ recv_p,        // [BSZ][NN][HH]
    const float* __restrict__ Wmsg1,   // [HH][2*HH]
    const float* __restrict__ W_hr, const float* __restrict__ W_hi,
    const float* __restrict__ W_hh,
    const float* __restrict__ W_ir, const float* __restrict__ b_ir,
    const float* __restrict__ W_ii, const float* __restrict__ b_ii,
    const float* __restrict__ W_in, const float* __restrict__ b_in,
    const float* __restrict__ W_o1, const float* __restrict__ b_o1,
    const float* __restrict__ W_o2, const float* __restrict__ b_o2,
    const float* __restrict__ W_o3, const float* __restrict__ b_o3,
    float* __restrict__ out,           // [BSZ][NSTEP][NN][HH]
    int t)
{
    __shared__ float sw[11 * LMAT];
    const int tid = threadIdx.x;

    for (int i = tid; i < HH * HH; i += 256) {
        const int row = i >> 5, col = i & 31;
        const int p = row * LROW + col;
        sw[M_IR * LMAT + p] = W_ir[i];
        sw[M_II * LMAT + p] = W_ii[i];
        sw[M_IN * LMAT + p] = W_in[i];
        sw[M_HR * LMAT + p] = W_hr[i];
        sw[M_HI * LMAT + p] = W_hi[i];
        sw[M_HH * LMAT + p] = W_hh[i];
        sw[M_O1 * LMAT + p] = W_o1[i];
        sw[M_O2 * LMAT + p] = W_o2[i];
        sw[M_O3 * LMAT + p] = W_o3[i];
        sw[M_SE * LMAT + p] = Wmsg1[row * 64 + col];        // W_send
        sw[M_RE * LMAT + p] = Wmsg1[row * 64 + 32 + col];   // W_recv
    }
    __syncthreads();

    const int grp = tid >> 5;                 // node group within block
    const int h   = tid & 31;                 // owned output element
    const int node = blockIdx.x * 8 + grp;    // < BSZ*NN
    const int b = node / NN;
    const int r = node - b * NN;

    const float inp = emb[(size_t)skill[b * TT + t] * HH + h];
    const float a   = agg[(size_t)node * HH + h];
    const float hid = hidden[(size_t)node * HH + h];

    float s_r = b_ir[h], s_i = b_ii[h], s_n = b_in[h];
    float g_r = 0.f, g_i = 0.f, g_h = 0.f;
#pragma unroll
    for (int k = 0; k < 32; ++k) {
        const float ik = __shfl(inp, k, 32);
        const float ak = __shfl(a, k, 32);
        const int p = h * LROW + k;
        s_r += ik * sw[M_IR * LMAT + p];
        s_i += ik * sw[M_II * LMAT + p];
        s_n += ik * sw[M_IN * LMAT + p];
        g_r += ak * sw[M_HR * LMAT + p];
        g_i += ak * sw[M_HI * LMAT + p];
        g_h += ak * sw[M_HH * LMAT + p];
    }
    const float rg = fast_sigmoid(s_r + g_r);
    const float ig = fast_sigmoid(s_i + g_i);
    const float nst = fast_tanh(s_n + rg * g_h);
    const float hn = (1.0f - ig) * nst + ig * hid;

    hidden[(size_t)node * HH + h] = hn;

    float snd = 0.f, rcv = 0.f, p1 = b_o1[h];
#pragma unroll
    for (int k = 0; k < 32; ++k) {
        const float hk = __shfl(hn, k, 32);
        const int p = h * LROW + k;
        snd += hk * sw[M_SE * LMAT + p];
        rcv += hk * sw[M_RE * LMAT + p];
        p1  += hk * sw[M_O1 * LMAT + p];
    }
    send_p[(size_t)node * HH + h] = snd;
    recv_p[(size_t)node * HH + h] = rcv;
    p1 = relu(p1);

    float p2 = b_o2[h];
#pragma unroll
    for (int k = 0; k < 32; ++k)
        p2 += __shfl(p1, k, 32) * sw[M_O2 * LMAT + h * LROW + k];
    p2 = relu(p2);

    float o = b_o3[h];
#pragma unroll
    for (int k = 0; k < 32; ++k)
        o += __shfl(p2, k, 32) * sw[M_O3 * LMAT + h * LROW + k];

    out[(((size_t)b * NSTEP + t) * NN + r) * HH + h] = o;
}

extern "C" void kernel_launch(void* const* d_in, const int* in_sizes, int n_in,
                              void* d_out, int out_size, void* d_ws, size_t ws_size,
                              hipStream_t stream) {
    const int*   skill = (const int*)d_in[0];
    const float* adj   = (const float*)d_in[1];
    const float* emb   = (const float*)d_in[2];
    const float* Wmsg1 = (const float*)d_in[3];
    const float* bmsg1 = (const float*)d_in[4];
    const float* Wmsg2 = (const float*)d_in[5];
    const float* bmsg2 = (const float*)d_in[6];
    const float* W_hr  = (const float*)d_in[7];
    const float* W_hi  = (const float*)d_in[8];
    const float* W_hh  = (const float*)d_in[9];
    const float* W_ir  = (const float*)d_in[10];
    const float* b_ir  = (const float*)d_in[11];
    const float* W_ii  = (const float*)d_in[12];
    const float* b_ii  = (const float*)d_in[13];
    const float* W_in  = (const float*)d_in[14];
    const float* b_in  = (const float*)d_in[15];
    const float* W_o1  = (const float*)d_in[16];
    const float* b_o1  = (const float*)d_in[17];
    const float* W_o2  = (const float*)d_in[18];
    const float* b_o2  = (const float*)d_in[19];
    const float* W_o3  = (const float*)d_in[20];
    const float* b_o3  = (const float*)d_in[21];
    float* out = (float*)d_out;

    const size_t NH = (size_t)BSZ * NN * HH;   // 196608
    float* hidden = (float*)d_ws;
    float* sendp  = hidden + NH;
    float* recvp  = sendp + NH;
    float* aggb   = recvp + NH;

    // hidden = send_p = recv_p = 0 at t=0 (contiguous)
    hipMemsetAsync(hidden, 0, 3 * NH * sizeof(float), stream);

    for (int t = 0; t < NSTEP; ++t) {
        k_agg<<<(BSZ * NN) / 4, 256, 0, stream>>>(sendp, recvp, adj, Wmsg2, bmsg1, bmsg2, aggb);
        k_update<<<(BSZ * NN) / 8, 256, 0, stream>>>(
            skill, emb, aggb, hidden, sendp, recvp, Wmsg1,
            W_hr, W_hi, W_hh, W_ir, b_ir, W_ii, b_ii, W_in, b_in,
            W_o1, b_o1, W_o2, b_o2, W_o3, b_o3, out, t);
    }
}

// Round 3
// 1674.676 us; speedup vs baseline: 39.3879x; 1.1999x over previous
//
#include <hip/hip_runtime.h>
#include <hip/hip_bf16.h>

#define BSZ 32
#define TT 50
#define NN 192
#define HH 32
#define NSTEP (TT - 1)

typedef __attribute__((ext_vector_type(8))) short bf16x8;
typedef __attribute__((ext_vector_type(4))) float f32x4;

#define MFMA16(A, B, C) __builtin_amdgcn_mfma_f32_16x16x32_bf16((A), (B), (C), 0, 0, 0)

__device__ __forceinline__ float fast_rcp(float x) { return __builtin_amdgcn_rcpf(x); }
__device__ __forceinline__ float fast_tanh(float x) {
    float e = __expf(2.0f * x);
    return 1.0f - 2.0f * fast_rcp(e + 1.0f);
}
__device__ __forceinline__ float fast_sigmoid(float x) { return fast_rcp(1.0f + __expf(-x)); }
__device__ __forceinline__ float relu(float x) { return x > 0.0f ? x : 0.0f; }

union U8 { bf16x8 v; __hip_bfloat162 p[4]; };

__device__ __forceinline__ void ld8(const float* p, float* x) {
    const float4* q = (const float4*)p;
    float4 a = q[0], c = q[1];
    x[0] = a.x; x[1] = a.y; x[2] = a.z; x[3] = a.w;
    x[4] = c.x; x[5] = c.y; x[6] = c.z; x[7] = c.w;
}

__device__ __forceinline__ bf16x8 pack8(const float* x) {
    U8 u;
#pragma unroll
    for (int i = 0; i < 4; ++i)
        u.p[i] = __float22bfloat162_rn(make_float2(x[2 * i], x[2 * i + 1]));
    return u.v;
}

// split x (8 fp32) into hi+lo bf16 pair: x ~= hi + lo to ~2^-16 relative
__device__ __forceinline__ void split8(const float* x, bf16x8& hi, bf16x8& lo) {
    U8 H, L;
#pragma unroll
    for (int i = 0; i < 4; ++i) {
        __hip_bfloat162 h = __float22bfloat162_rn(make_float2(x[2 * i], x[2 * i + 1]));
        float2 hf = __bfloat1622float2(h);
        H.p[i] = h;
        L.p[i] = __float22bfloat162_rn(make_float2(x[2 * i] - hf.x, x[2 * i + 1] - hf.y));
    }
    hi = H.v; lo = L.v;
}

__device__ __forceinline__ void loadB_hl(const float* Wrow, bf16x8& h, bf16x8& l) {
    float x[8];
    ld8(Wrow, x);
    split8(x, h, l);
}

// One recurrence step, fully fused.
// Block: 512 threads = 8 waves = 8 consecutive nodes (same b, since 192 % 8 == 0).
// Phase A (per wave): msg1-tanh -> bf16 MFMA vs W2^T -> tanh -> adj-weighted sum = agg (to LDS).
// Phase B (wave 0): batched-8-node MFMA GRU update + send/recv proj + 3-layer head,
//                   bf16 hi/lo split operands (~fp32 precision).
__global__ __launch_bounds__(512, 4) void k_step(
    const int* __restrict__ skill, const float* __restrict__ adj,
    const float* __restrict__ emb,
    const float* __restrict__ Wmsg1, const float* __restrict__ bmsg1,
    const float* __restrict__ Wmsg2, const float* __restrict__ bmsg2,
    const float* __restrict__ W_hr, const float* __restrict__ W_hi, const float* __restrict__ W_hh,
    const float* __restrict__ W_ir, const float* __restrict__ b_ir,
    const float* __restrict__ W_ii, const float* __restrict__ b_ii,
    const float* __restrict__ W_in, const float* __restrict__ b_in,
    const float* __restrict__ W_o1, const float* __restrict__ b_o1,
    const float* __restrict__ W_o2, const float* __restrict__ b_o2,
    const float* __restrict__ W_o3, const float* __restrict__ b_o3,
    float* __restrict__ hidden, float* __restrict__ send_p, float* __restrict__ recv_p,
    float* __restrict__ out, int t)
{
    __shared__ float spsh[NN][36];    // send_p[b] staged, padded rows
    __shared__ float adjsh[8][NN];    // per-wave adj rows
    __shared__ float aggsh[16][36];   // phase-A result (rows 0-7 valid)
    __shared__ float hnsh[16][36];
    __shared__ float p1sh[16][36];
    __shared__ float p2sh[16][36];

    const int tid = threadIdx.x;
    const int w = tid >> 6, lane = tid & 63;
    const int n16 = lane & 15, kg = lane >> 4, k8 = kg * 8;
    const int node0 = blockIdx.x * 8;
    const int b = node0 / NN;
    const int node = node0 + w;

    // ---- cooperative stage of send_p[b] (24 KB) ----
    {
        const float* sb = send_p + (size_t)b * NN * HH;
        for (int i = tid; i < NN * HH; i += 512)
            spsh[i >> 5][i & 31] = sb[i];
    }
    // ---- per-wave adj row (coalesced) ----
    adjsh[w][lane]       = adj[(size_t)node * NN + lane];
    adjsh[w][lane + 64]  = adj[(size_t)node * NN + lane + 64];
    adjsh[w][lane + 128] = adj[(size_t)node * NN + lane + 128];

    // rv8 = recv_p[node][k8..k8+7] + b_msg1 (folded)
    float rv8[8];
    {
        float r[8], c[8];
        ld8(recv_p + (size_t)node * HH + k8, r);
        ld8(bmsg1 + k8, c);
#pragma unroll
        for (int i = 0; i < 8; ++i) rv8[i] = r[i] + c[i];
    }
    // B-frags: B[k][n] = W2^T[k][n] = W2[half*16+n16][k]
    bf16x8 Bf0, Bf1;
    {
        float x[8];
        ld8(Wmsg2 + (size_t)n16 * HH + k8, x);        Bf0 = pack8(x);
        ld8(Wmsg2 + (size_t)(16 + n16) * HH + k8, x); Bf1 = pack8(x);
    }
    const float bb2_0 = bmsg2[n16], bb2_1 = bmsg2[16 + n16];

    __syncthreads();

    // ================= Phase A =================
    float acc0 = 0.f, acc1 = 0.f;
#pragma unroll
    for (int s0 = 0; s0 < NN; s0 += 16) {
        float v[8], tv[8];
        ld8(&spsh[s0 + n16][k8], v);
#pragma unroll
        for (int i = 0; i < 8; ++i) tv[i] = fast_tanh(rv8[i] + v[i]);
        bf16x8 A = pack8(tv);
        f32x4 c0 = MFMA16(A, Bf0, ((f32x4){bb2_0, bb2_0, bb2_0, bb2_0}));
        f32x4 c1 = MFMA16(A, Bf1, ((f32x4){bb2_1, bb2_1, bb2_1, bb2_1}));
        const float4 a4 = *(const float4*)(&adjsh[w][s0 + kg * 4]);
        acc0 += a4.x * fast_tanh(c0[0]) + a4.y * fast_tanh(c0[1]) +
                a4.z * fast_tanh(c0[2]) + a4.w * fast_tanh(c0[3]);
        acc1 += a4.x * fast_tanh(c1[0]) + a4.y * fast_tanh(c1[1]) +
                a4.z * fast_tanh(c1[2]) + a4.w * fast_tanh(c1[3]);
    }
    acc0 += __shfl_xor(acc0, 16, 64); acc0 += __shfl_xor(acc0, 32, 64);
    acc1 += __shfl_xor(acc1, 16, 64); acc1 += __shfl_xor(acc1, 32, 64);
    if (kg == 0) {
        aggsh[w][n16]      = acc0 * (1.0f / (float)NN);
        aggsh[w][16 + n16] = acc1 * (1.0f / (float)NN);
    }
    __syncthreads();
    if (w != 0) return;

    // ================= Phase B (wave 0 only) =================
    bf16x8 Aagg_h, Aagg_l, Ainp_h, Ainp_l;
    {
        float x[8];
        ld8(&aggsh[n16][k8], x);
        split8(x, Aagg_h, Aagg_l);
        const float* erow = emb + (size_t)skill[b * TT + t] * HH;
        ld8(erow + k8, x);
        split8(x, Ainp_h, Ainp_l);
    }

    // gates + hn  (D layout: col = lane&15 -> h = hf*16+n16, row(node) = 4*kg+j)
#pragma unroll
    for (int hf = 0; hf < 2; ++hf) {
        const int rowb = hf * 16 + n16;
        bf16x8 Bh, Bl, Ch, Cl;

        f32x4 Cr = {b_ir[rowb], b_ir[rowb], b_ir[rowb], b_ir[rowb]};
        loadB_hl(W_hr + rowb * HH + k8, Bh, Bl);
        loadB_hl(W_ir + rowb * HH + k8, Ch, Cl);
        Cr = MFMA16(Aagg_h, Bh, Cr); Cr = MFMA16(Aagg_h, Bl, Cr); Cr = MFMA16(Aagg_l, Bh, Cr);
        Cr = MFMA16(Ainp_h, Ch, Cr); Cr = MFMA16(Ainp_h, Cl, Cr); Cr = MFMA16(Ainp_l, Ch, Cr);

        f32x4 Ci = {b_ii[rowb], b_ii[rowb], b_ii[rowb], b_ii[rowb]};
        loadB_hl(W_hi + rowb * HH + k8, Bh, Bl);
        loadB_hl(W_ii + rowb * HH + k8, Ch, Cl);
        Ci = MFMA16(Aagg_h, Bh, Ci); Ci = MFMA16(Aagg_h, Bl, Ci); Ci = MFMA16(Aagg_l, Bh, Ci);
        Ci = MFMA16(Ainp_h, Ch, Ci); Ci = MFMA16(Ainp_h, Cl, Ci); Ci = MFMA16(Ainp_l, Ch, Ci);

        f32x4 Cn = {b_in[rowb], b_in[rowb], b_in[rowb], b_in[rowb]};
        loadB_hl(W_in + rowb * HH + k8, Ch, Cl);
        Cn = MFMA16(Ainp_h, Ch, Cn); Cn = MFMA16(Ainp_h, Cl, Cn); Cn = MFMA16(Ainp_l, Ch, Cn);

        f32x4 Cg = {0.f, 0.f, 0.f, 0.f};
        loadB_hl(W_hh + rowb * HH + k8, Bh, Bl);
        Cg = MFMA16(Aagg_h, Bh, Cg); Cg = MFMA16(Aagg_h, Bl, Cg); Cg = MFMA16(Aagg_l, Bh, Cg);

#pragma unroll
        for (int j = 0; j < 4; ++j) {
            float rg = fast_sigmoid(Cr[j]);
            float ig = fast_sigmoid(Ci[j]);
            float ns = fast_tanh(Cn[j] + rg * Cg[j]);
            if (kg < 2) {
                const int row = 4 * kg + j;
                float* hp = hidden + (size_t)(node0 + row) * HH + rowb;
                float hv = *hp;
                float hn = (1.f - ig) * ns + ig * hv;
                *hp = hn;
                hnsh[row][rowb] = hn;
            }
        }
    }

    bf16x8 Ahn_h, Ahn_l;
    {
        float x[8];
        ld8(&hnsh[n16][k8], x);
        split8(x, Ahn_h, Ahn_l);
    }

    // send/recv projections + head layer 1
#pragma unroll
    for (int hf = 0; hf < 2; ++hf) {
        const int rowb = hf * 16 + n16;
        bf16x8 Bh, Bl;

        f32x4 Cs = {0.f, 0.f, 0.f, 0.f};
        loadB_hl(Wmsg1 + (size_t)rowb * 2 * HH + k8, Bh, Bl);          // W_send row
        Cs = MFMA16(Ahn_h, Bh, Cs); Cs = MFMA16(Ahn_h, Bl, Cs); Cs = MFMA16(Ahn_l, Bh, Cs);

        f32x4 Cv = {0.f, 0.f, 0.f, 0.f};
        loadB_hl(Wmsg1 + (size_t)rowb * 2 * HH + HH + k8, Bh, Bl);     // W_recv row
        Cv = MFMA16(Ahn_h, Bh, Cv); Cv = MFMA16(Ahn_h, Bl, Cv); Cv = MFMA16(Ahn_l, Bh, Cv);

        f32x4 Cp = {b_o1[rowb], b_o1[rowb], b_o1[rowb], b_o1[rowb]};
        loadB_hl(W_o1 + rowb * HH + k8, Bh, Bl);
        Cp = MFMA16(Ahn_h, Bh, Cp); Cp = MFMA16(Ahn_h, Bl, Cp); Cp = MFMA16(Ahn_l, Bh, Cp);

#pragma unroll
        for (int j = 0; j < 4; ++j) {
            if (kg < 2) {
                const int row = 4 * kg + j;
                send_p[(size_t)(node0 + row) * HH + rowb] = Cs[j];
                recv_p[(size_t)(node0 + row) * HH + rowb] = Cv[j];
                p1sh[row][rowb] = relu(Cp[j]);
            }
        }
    }

    bf16x8 Ap_h, Ap_l;
    {
        float x[8];
        ld8(&p1sh[n16][k8], x);
        split8(x, Ap_h, Ap_l);
    }
#pragma unroll
    for (int hf = 0; hf < 2; ++hf) {
        const int rowb = hf * 16 + n16;
        bf16x8 Bh, Bl;
        f32x4 Cq = {b_o2[rowb], b_o2[rowb], b_o2[rowb], b_o2[rowb]};
        loadB_hl(W_o2 + rowb * HH + k8, Bh, Bl);
        Cq = MFMA16(Ap_h, Bh, Cq); Cq = MFMA16(Ap_h, Bl, Cq); Cq = MFMA16(Ap_l, Bh, Cq);
#pragma unroll
        for (int j = 0; j < 4; ++j)
            if (kg < 2) p2sh[4 * kg + j][rowb] = relu(Cq[j]);
    }

    bf16x8 Aq_h, Aq_l;
    {
        float x[8];
        ld8(&p2sh[n16][k8], x);
        split8(x, Aq_h, Aq_l);
    }
    const int rbase = node0 - b * NN;
#pragma unroll
    for (int hf = 0; hf < 2; ++hf) {
        const int rowb = hf * 16 + n16;
        bf16x8 Bh, Bl;
        f32x4 Co = {b_o3[rowb], b_o3[rowb], b_o3[rowb], b_o3[rowb]};
        loadB_hl(W_o3 + rowb * HH + k8, Bh, Bl);
        Co = MFMA16(Aq_h, Bh, Co); Co = MFMA16(Aq_h, Bl, Co); Co = MFMA16(Aq_l, Bh, Co);
#pragma unroll
        for (int j = 0; j < 4; ++j) {
            if (kg < 2) {
                const int row = 4 * kg + j;
                out[(((size_t)b * NSTEP + t) * NN + rbase + row) * HH + rowb] = Co[j];
            }
        }
    }
}

extern "C" void kernel_launch(void* const* d_in, const int* in_sizes, int n_in,
                              void* d_out, int out_size, void* d_ws, size_t ws_size,
                              hipStream_t stream) {
    const int*   skill = (const int*)d_in[0];
    const float* adj   = (const float*)d_in[1];
    const float* emb   = (const float*)d_in[2];
    const float* Wmsg1 = (const float*)d_in[3];
    const float* bmsg1 = (const float*)d_in[4];
    const float* Wmsg2 = (const float*)d_in[5];
    const float* bmsg2 = (const float*)d_in[6];
    const float* W_hr  = (const float*)d_in[7];
    const float* W_hi  = (const float*)d_in[8];
    const float* W_hh  = (const float*)d_in[9];
    const float* W_ir  = (const float*)d_in[10];
    const float* b_ir  = (const float*)d_in[11];
    const float* W_ii  = (const float*)d_in[12];
    const float* b_ii  = (const float*)d_in[13];
    const float* W_in  = (const float*)d_in[14];
    const float* b_in  = (const float*)d_in[15];
    const float* W_o1  = (const float*)d_in[16];
    const float* b_o1  = (const float*)d_in[17];
    const float* W_o2  = (const float*)d_in[18];
    const float* b_o2  = (const float*)d_in[19];
    const float* W_o3  = (const float*)d_in[20];
    const float* b_o3  = (const float*)d_in[21];
    float* out = (float*)d_out;

    const size_t NH = (size_t)BSZ * NN * HH;   // 196608
    float* hidden = (float*)d_ws;
    float* sendp  = hidden + NH;
    float* recvp  = sendp + NH;

    // hidden = send_p = recv_p = 0 at t=0 (contiguous)
    hipMemsetAsync(hidden, 0, 3 * NH * sizeof(float), stream);

    for (int t = 0; t < NSTEP; ++t) {
        k_step<<<(BSZ * NN) / 8, 512, 0, stream>>>(
            skill, adj, emb, Wmsg1, bmsg1, Wmsg2, bmsg2,
            W_hr, W_hi, W_hh, W_ir, b_ir, W_ii, b_ii, W_in, b_in,
            W_o1, b_o1, W_o2, b_o2, W_o3, b_o3,
            hidden, sendp, recvp, out, t);
    }
}